// Round 4
// baseline (2609.927 us; speedup 1.0000x reference)
//
#include <hip/hip_runtime.h>

#define NN 300000   // nodes
#define DD 256      // D == H == 256
#define BB 1024     // graphs

__device__ __forceinline__ float gelu_exact(float v) {
    // jax.nn.gelu(approximate=False): 0.5*v*(1+erf(v/sqrt(2)))
    return 0.5f * v * (1.0f + erff(v * 0.70710678118654752f));
}

// ---------------------------------------------------------------------------
// Kernel 1: importance MLP.  imp[n] = (gelu(LN(x@wi1+bi1)*gi+bti) @ wi2) + bi2
// Block: 32 rows x 256 cols, 256 threads, acc[4][8] per thread.
// Column map: c(j) = tx*4 + (j&3) + (j>>2)*128   (two float4 groups)
// ---------------------------------------------------------------------------
__global__ __launch_bounds__(256, 2) void mlp_imp_kernel(
    const float* __restrict__ x,
    const float* __restrict__ w1, const float* __restrict__ b1,
    const float* __restrict__ g,  const float* __restrict__ bt,
    const float* __restrict__ w2, const float* __restrict__ b2,
    float* __restrict__ imp)
{
    __shared__ float ws[32 * 256];  // 32KB weight tile [k][c]
    __shared__ float xs[32 * 32];   // 4KB  x tile [r][k]
    const int t  = threadIdx.x;
    const int tx = t & 31, ty = t >> 5;
    const int r0 = blockIdx.x * 32;

    float acc[4][8];
    #pragma unroll
    for (int i = 0; i < 4; ++i)
        #pragma unroll
        for (int j = 0; j < 8; ++j) acc[i][j] = 0.0f;

    for (int kt = 0; kt < 8; ++kt) {
        // stage x tile: 1024 floats, 4 per thread, coalesced
        *reinterpret_cast<float4*>(&xs[(t >> 3) * 32 + (t & 7) * 4]) =
            *reinterpret_cast<const float4*>(&x[(size_t)(r0 + (t >> 3)) * DD + kt * 32 + (t & 7) * 4]);
        // stage weight tile: 8192 floats contiguous (rows kt*32..+31 of w1)
        #pragma unroll
        for (int u = 0; u < 8; ++u) {
            const int idx = u * 1024 + t * 4;
            *reinterpret_cast<float4*>(&ws[idx]) =
                *reinterpret_cast<const float4*>(&w1[kt * 8192 + idx]);
        }
        __syncthreads();
        #pragma unroll
        for (int k = 0; k < 32; ++k) {
            const float4 bv0 = *reinterpret_cast<const float4*>(&ws[k * 256 + tx * 4]);
            const float4 bv1 = *reinterpret_cast<const float4*>(&ws[k * 256 + tx * 4 + 128]);
            const float bc[8] = {bv0.x, bv0.y, bv0.z, bv0.w, bv1.x, bv1.y, bv1.z, bv1.w};
            #pragma unroll
            for (int i = 0; i < 4; ++i) {
                const float a = xs[(ty * 4 + i) * 32 + k];  // broadcast read
                #pragma unroll
                for (int j = 0; j < 8; ++j) acc[i][j] = fmaf(a, bc[j], acc[i][j]);
            }
        }
        __syncthreads();
    }

    // per-column params
    const float4 b1a = *reinterpret_cast<const float4*>(&b1[tx * 4]);
    const float4 b1b = *reinterpret_cast<const float4*>(&b1[tx * 4 + 128]);
    const float4 ga  = *reinterpret_cast<const float4*>(&g[tx * 4]);
    const float4 gb  = *reinterpret_cast<const float4*>(&g[tx * 4 + 128]);
    const float4 bta = *reinterpret_cast<const float4*>(&bt[tx * 4]);
    const float4 btb = *reinterpret_cast<const float4*>(&bt[tx * 4 + 128]);
    const float4 w2a = *reinterpret_cast<const float4*>(&w2[tx * 4]);
    const float4 w2b = *reinterpret_cast<const float4*>(&w2[tx * 4 + 128]);
    const float bcol[8]  = {b1a.x, b1a.y, b1a.z, b1a.w, b1b.x, b1b.y, b1b.z, b1b.w};
    const float gcol[8]  = {ga.x, ga.y, ga.z, ga.w, gb.x, gb.y, gb.z, gb.w};
    const float btcol[8] = {bta.x, bta.y, bta.z, bta.w, btb.x, btb.y, btb.z, btb.w};
    const float w2col[8] = {w2a.x, w2a.y, w2a.z, w2a.w, w2b.x, w2b.y, w2b.z, w2b.w};
    const float b2v = b2[0];

    #pragma unroll
    for (int i = 0; i < 4; ++i) {
        float s1 = 0.0f, s2 = 0.0f;
        #pragma unroll
        for (int j = 0; j < 8; ++j) {
            float h = acc[i][j] + bcol[j];
            acc[i][j] = h;
            s1 += h;
            s2 += h * h;
        }
        #pragma unroll
        for (int m = 1; m < 32; m <<= 1) { s1 += __shfl_xor(s1, m); s2 += __shfl_xor(s2, m); }
        const float mean = s1 * (1.0f / 256.0f);
        const float var  = s2 * (1.0f / 256.0f) - mean * mean;
        const float inv  = rsqrtf(var + 1e-5f);
        float p = 0.0f;
        #pragma unroll
        for (int j = 0; j < 8; ++j) {
            const float hn = (acc[i][j] - mean) * inv * gcol[j] + btcol[j];
            p += gelu_exact(hn) * w2col[j];
        }
        #pragma unroll
        for (int m = 1; m < 32; m <<= 1) p += __shfl_xor(p, m);
        if (tx == 0) imp[r0 + ty * 4 + i] = p + b2v;
    }
}

// ---------------------------------------------------------------------------
// Kernel 2a: segment max via order-preserving uint atomicMax (segmax memset 0:
// mapped-0 unmaps to -NaN, below every real value -> identity)
// ---------------------------------------------------------------------------
__global__ void segmax_kernel(const float* __restrict__ imp, const int* __restrict__ batch,
                              unsigned* __restrict__ segmax)
{
    const int n = blockIdx.x * blockDim.x + threadIdx.x;
    if (n >= NN) return;
    unsigned u = __float_as_uint(imp[n]);
    u = (u & 0x80000000u) ? ~u : (u | 0x80000000u);
    atomicMax(&segmax[batch[n]], u);
}

// ---------------------------------------------------------------------------
// Kernel 2b: e = exp(imp - segmax[b]) stored in place; segsum += e
// ---------------------------------------------------------------------------
__global__ void segexp_kernel(float* __restrict__ imp, const int* __restrict__ batch,
                              const unsigned* __restrict__ segmax, float* __restrict__ segsum)
{
    const int n = blockIdx.x * blockDim.x + threadIdx.x;
    if (n >= NN) return;
    const int b = batch[n];
    unsigned u = segmax[b];
    const float mx = (u & 0x80000000u) ? __uint_as_float(u ^ 0x80000000u)
                                       : __uint_as_float(~u);
    const float e = expf(imp[n] - mx);
    imp[n] = e;
    atomicAdd(&segsum[b], e);
}

// ---------------------------------------------------------------------------
// Kernel 3: feature MLP + weighted scatter-add.
// Phase A: f = gelu(LN(x@wf1+bf1)*gf+btf) -> fbuf (LDS, 32KB)
// Phase B: tf = f @ wf2 + bf2
// Phase C: out[batch[r]] += tf[r] * (e[r]/segsum[batch[r]]) with
//          per-thread 4-row combine + cross-half-wave (xor 32) combine.
// LDS: ws 32KB + fbuf 32KB = 64KB (x tile aliases fbuf head). 2 blocks/CU.
// ---------------------------------------------------------------------------
__global__ __launch_bounds__(256, 2) void mlp_feat_kernel(
    const float* __restrict__ x, const int* __restrict__ batch,
    const float* __restrict__ w1, const float* __restrict__ b1,
    const float* __restrict__ g,  const float* __restrict__ bt,
    const float* __restrict__ w2, const float* __restrict__ b2f,
    const float* __restrict__ e, const float* __restrict__ segsum,
    float* __restrict__ out)
{
    __shared__ float ws[32 * 256];    // 32KB weight tile
    __shared__ float fbuf[32 * 256];  // 32KB f tile; head 4KB doubles as x tile
    float* xs = fbuf;
    const int t  = threadIdx.x;
    const int tx = t & 31, ty = t >> 5;
    const int r0 = blockIdx.x * 32;

    float acc[4][8];
    #pragma unroll
    for (int i = 0; i < 4; ++i)
        #pragma unroll
        for (int j = 0; j < 8; ++j) acc[i][j] = 0.0f;

    // ---- Phase A: x @ wf1 ----
    for (int kt = 0; kt < 8; ++kt) {
        *reinterpret_cast<float4*>(&xs[(t >> 3) * 32 + (t & 7) * 4]) =
            *reinterpret_cast<const float4*>(&x[(size_t)(r0 + (t >> 3)) * DD + kt * 32 + (t & 7) * 4]);
        #pragma unroll
        for (int u = 0; u < 8; ++u) {
            const int idx = u * 1024 + t * 4;
            *reinterpret_cast<float4*>(&ws[idx]) =
                *reinterpret_cast<const float4*>(&w1[kt * 8192 + idx]);
        }
        __syncthreads();
        #pragma unroll
        for (int k = 0; k < 32; ++k) {
            const float4 bv0 = *reinterpret_cast<const float4*>(&ws[k * 256 + tx * 4]);
            const float4 bv1 = *reinterpret_cast<const float4*>(&ws[k * 256 + tx * 4 + 128]);
            const float bc[8] = {bv0.x, bv0.y, bv0.z, bv0.w, bv1.x, bv1.y, bv1.z, bv1.w};
            #pragma unroll
            for (int i = 0; i < 4; ++i) {
                const float a = xs[(ty * 4 + i) * 32 + k];
                #pragma unroll
                for (int j = 0; j < 8; ++j) acc[i][j] = fmaf(a, bc[j], acc[i][j]);
            }
        }
        __syncthreads();
    }

    // ---- LN + GELU -> fbuf ----
    {
        const float4 b1a = *reinterpret_cast<const float4*>(&b1[tx * 4]);
        const float4 b1b = *reinterpret_cast<const float4*>(&b1[tx * 4 + 128]);
        const float4 ga  = *reinterpret_cast<const float4*>(&g[tx * 4]);
        const float4 gb  = *reinterpret_cast<const float4*>(&g[tx * 4 + 128]);
        const float4 bta = *reinterpret_cast<const float4*>(&bt[tx * 4]);
        const float4 btb = *reinterpret_cast<const float4*>(&bt[tx * 4 + 128]);
        const float bcol[8]  = {b1a.x, b1a.y, b1a.z, b1a.w, b1b.x, b1b.y, b1b.z, b1b.w};
        const float gcol[8]  = {ga.x, ga.y, ga.z, ga.w, gb.x, gb.y, gb.z, gb.w};
        const float btcol[8] = {bta.x, bta.y, bta.z, bta.w, btb.x, btb.y, btb.z, btb.w};
        #pragma unroll
        for (int i = 0; i < 4; ++i) {
            float s1 = 0.0f, s2 = 0.0f;
            #pragma unroll
            for (int j = 0; j < 8; ++j) {
                float h = acc[i][j] + bcol[j];
                acc[i][j] = h;
                s1 += h;
                s2 += h * h;
            }
            #pragma unroll
            for (int m = 1; m < 32; m <<= 1) { s1 += __shfl_xor(s1, m); s2 += __shfl_xor(s2, m); }
            const float mean = s1 * (1.0f / 256.0f);
            const float var  = s2 * (1.0f / 256.0f) - mean * mean;
            const float inv  = rsqrtf(var + 1e-5f);
            #pragma unroll
            for (int j = 0; j < 8; ++j) {
                const float hn = (acc[i][j] - mean) * inv * gcol[j] + btcol[j];
                const int   c  = tx * 4 + (j & 3) + ((j >> 2) << 7);
                fbuf[(ty * 4 + i) * 256 + c] = gelu_exact(hn);
            }
        }
    }

    // ---- Phase B: tf = f @ wf2 ----
    float acc2[4][8];
    #pragma unroll
    for (int i = 0; i < 4; ++i)
        #pragma unroll
        for (int j = 0; j < 8; ++j) acc2[i][j] = 0.0f;

    for (int kt = 0; kt < 8; ++kt) {
        #pragma unroll
        for (int u = 0; u < 8; ++u) {
            const int idx = u * 1024 + t * 4;
            *reinterpret_cast<float4*>(&ws[idx]) =
                *reinterpret_cast<const float4*>(&w2[kt * 8192 + idx]);
        }
        __syncthreads();  // on kt==0 also publishes fbuf writes
        #pragma unroll
        for (int k = 0; k < 32; ++k) {
            const float4 bv0 = *reinterpret_cast<const float4*>(&ws[k * 256 + tx * 4]);
            const float4 bv1 = *reinterpret_cast<const float4*>(&ws[k * 256 + tx * 4 + 128]);
            const float bc[8] = {bv0.x, bv0.y, bv0.z, bv0.w, bv1.x, bv1.y, bv1.z, bv1.w};
            #pragma unroll
            for (int i = 0; i < 4; ++i) {
                const float a = fbuf[(ty * 4 + i) * 256 + kt * 32 + k];
                #pragma unroll
                for (int j = 0; j < 8; ++j) acc2[i][j] = fmaf(a, bc[j], acc2[i][j]);
            }
        }
        __syncthreads();
    }

    // ---- Phase C: weighted scatter-add ----
    const float4 f2a = *reinterpret_cast<const float4*>(&b2f[tx * 4]);
    const float4 f2b = *reinterpret_cast<const float4*>(&b2f[tx * 4 + 128]);
    const float fcol[8] = {f2a.x, f2a.y, f2a.z, f2a.w, f2b.x, f2b.y, f2b.z, f2b.w};
    int cj[8];
    #pragma unroll
    for (int j = 0; j < 8; ++j) cj[j] = tx * 4 + (j & 3) + ((j >> 2) << 7);

    int   bi[4];
    float wgt[4];
    #pragma unroll
    for (int i = 0; i < 4; ++i) {
        const int r = r0 + ty * 4 + i;
        bi[i]  = batch[r];
        wgt[i] = e[r] / segsum[bi[i]];
    }
    const bool uni = (bi[0] == bi[1]) && (bi[1] == bi[2]) && (bi[2] == bi[3]);
    const int  pb   = __shfl_xor(bi[0], 32);
    const int  puni = __shfl_xor((int)uni, 32);
    const bool pair = uni && puni && (pb == bi[0]);

    if (uni) {
        #pragma unroll
        for (int j = 0; j < 8; ++j) {
            float s = (acc2[0][j] + fcol[j]) * wgt[0]
                    + (acc2[1][j] + fcol[j]) * wgt[1]
                    + (acc2[2][j] + fcol[j]) * wgt[2]
                    + (acc2[3][j] + fcol[j]) * wgt[3];
            const float ps = __shfl_xor(s, 32);
            if (pair) {
                if ((t & 63) < 32) atomicAdd(&out[bi[0] * 256 + cj[j]], s + ps);
            } else {
                atomicAdd(&out[bi[0] * 256 + cj[j]], s);
            }
        }
    } else {
        #pragma unroll
        for (int i = 0; i < 4; ++i)
            #pragma unroll
            for (int j = 0; j < 8; ++j)
                atomicAdd(&out[bi[i] * 256 + cj[j]], (acc2[i][j] + fcol[j]) * wgt[i]);
    }
}

// ---------------------------------------------------------------------------
extern "C" void kernel_launch(void* const* d_in, const int* in_sizes, int n_in,
                              void* d_out, int out_size, void* d_ws, size_t ws_size,
                              hipStream_t stream)
{
    const float* x    = (const float*)d_in[0];
    const int*   batch= (const int*)  d_in[1];
    const float* wi1  = (const float*)d_in[2];
    const float* bi1  = (const float*)d_in[3];
    const float* gi   = (const float*)d_in[4];
    const float* bti  = (const float*)d_in[5];
    const float* wi2  = (const float*)d_in[6];
    const float* bi2  = (const float*)d_in[7];
    const float* wf1  = (const float*)d_in[8];
    const float* bf1  = (const float*)d_in[9];
    const float* gf   = (const float*)d_in[10];
    const float* btf  = (const float*)d_in[11];
    const float* wf2  = (const float*)d_in[12];
    const float* bf2  = (const float*)d_in[13];
    float* out = (float*)d_out;

    // workspace layout: imp/e [NN] f32 | segmax [BB] u32 | segsum [BB] f32
    float*    imp    = (float*)d_ws;
    unsigned* segmax = (unsigned*)((char*)d_ws + (size_t)NN * 4);
    float*    segsum = (float*)((char*)d_ws + (size_t)NN * 4 + (size_t)BB * 4);

    hipMemsetAsync(d_out, 0, (size_t)BB * DD * sizeof(float), stream);
    hipMemsetAsync((void*)segmax, 0, (size_t)BB * 2 * sizeof(float), stream);

    mlp_imp_kernel<<<NN / 32, 256, 0, stream>>>(x, wi1, bi1, gi, bti, wi2, bi2, imp);
    segmax_kernel<<<(NN + 255) / 256, 256, 0, stream>>>(imp, batch, segmax);
    segexp_kernel<<<(NN + 255) / 256, 256, 0, stream>>>(imp, batch, segmax, segsum);
    mlp_feat_kernel<<<NN / 32, 256, 0, stream>>>(x, batch, wf1, bf1, gf, btf, wf2, bf2,
                                                 imp, segsum, out);
}

// Round 5
// 1474.895 us; speedup vs baseline: 1.7696x; 1.7696x over previous
//
#include <hip/hip_runtime.h>

#define NN 300000   // nodes
#define DD 256      // D == H == 256
#define BB 1024     // graphs

typedef short bf16x8 __attribute__((ext_vector_type(8)));
typedef float f32x4  __attribute__((ext_vector_type(4)));

__device__ __forceinline__ float gelu_exact(float v) {
    return 0.5f * v * (1.0f + erff(v * 0.70710678118654752f));
}
// fp32 -> bf16 RNE (bits)
__device__ __forceinline__ unsigned short f2bf(float f) {
    unsigned u = __float_as_uint(f);
    return (unsigned short)((u + 0x7fffu + ((u >> 16) & 1u)) >> 16);
}
__device__ __forceinline__ float bf2f(unsigned short h) {
    return __uint_as_float(((unsigned)h) << 16);
}

// ---------------------------------------------------------------------------
// Weight pre-conversion: w[256][256] fp32 (row-major [k][n]) -> fragment-tiled
// split-bf16: dst ushort idx = kt*16384 + part*8192 + ntile*512 + lane*8 + j
// where k = kt*32 + (lane>>4)*8 + j, n = ntile*16 + (lane&15), part0=hi part1=lo.
// GEMM then stages one kt-tile (32KB) as a pure linear copy, and B-fragment
// reads are lane-linear 16B (conflict-free). k-grouping assumption matches the
// A-side staging, so any k-permutation error cancels in the MFMA dot product.
// ---------------------------------------------------------------------------
__global__ void convert_weights_kernel(const float* __restrict__ w1,
                                       const float* __restrict__ wf1,
                                       const float* __restrict__ wf2,
                                       unsigned short* __restrict__ c1,
                                       unsigned short* __restrict__ cf1,
                                       unsigned short* __restrict__ cf2)
{
    const int tid = blockIdx.x * 256 + threadIdx.x;   // 3*65536 total
    const int mat = tid >> 16;
    const int rem = tid & 65535;
    const int k = rem >> 8, n = rem & 255;
    const float* src = (mat == 0) ? w1 : (mat == 1) ? wf1 : wf2;
    unsigned short* dst = (mat == 0) ? c1 : (mat == 1) ? cf1 : cf2;
    const float f = src[rem];
    const unsigned short hi = f2bf(f);
    const unsigned short lo = f2bf(f - bf2f(hi));
    const int kt = k >> 5, gg = (k >> 3) & 3, j = k & 7;
    const int ntile = n >> 4, nlo = n & 15;
    const int base = kt * 16384 + ntile * 512 + (gg * 16 + nlo) * 8 + j;
    dst[base] = hi;
    dst[base + 8192] = lo;
}

// ---------------------------------------------------------------------------
// Kernel 1: importance MLP via split-bf16 MFMA.
// Block: 32 rows, 256 threads = 4 waves; wave w owns cols [w*64, w*64+64).
// acc[mt][f] : mt in {0,1} row-tiles of 16, f in {0..3} col-tiles of 16.
// C/D map (verified m89/m91): col = w*64+f*16+(lane&15), row = mt*16+(lane>>4)*4+reg.
// LDS: Ahi/Alo 16KB each (x fragments), Bb 32KB (one kt weight tile), red 1KB.
// 65KB -> 2 blocks/CU.
// ---------------------------------------------------------------------------
__global__ __launch_bounds__(256, 2) void mlp_imp_mfma(
    const float* __restrict__ x, const unsigned short* __restrict__ wc,
    const float* __restrict__ b1, const float* __restrict__ gam,
    const float* __restrict__ bt, const float* __restrict__ w2,
    const float* __restrict__ b2, float* __restrict__ imp)
{
    __shared__ __align__(16) unsigned short Ahi[8192];  // [kt*2+mt][lane][j]
    __shared__ __align__(16) unsigned short Alo[8192];
    __shared__ __align__(16) unsigned short Bb[16384];  // [part][ntile][lane][j]
    __shared__ float red[256];                          // [row(32)][8]
    const int t = threadIdx.x;
    const int w = t >> 6, l = t & 63;
    const int nl = l & 15, gq = l >> 4;
    const int r0 = blockIdx.x * 32;

    // ---- stage x -> split-bf16 A fragments (frag-ordered, k-grouping = B's) ----
    {
        const int rr = t >> 6;               // base row 0..3
        const int c0 = (t & 63) * 4;         // k-chunk of 4
        const int kt = c0 >> 5, gg = (c0 >> 3) & 3, j0 = c0 & 7;
        #pragma unroll
        for (int p = 0; p < 8; ++p) {
            const int r = rr + p * 4;
            const float4 v = *reinterpret_cast<const float4*>(&x[(size_t)(r0 + r) * DD + c0]);
            const unsigned short h0 = f2bf(v.x), h1 = f2bf(v.y), h2 = f2bf(v.z), h3 = f2bf(v.w);
            const unsigned short o0 = f2bf(v.x - bf2f(h0)), o1 = f2bf(v.y - bf2f(h1));
            const unsigned short o2 = f2bf(v.z - bf2f(h2)), o3 = f2bf(v.w - bf2f(h3));
            const int idx = (kt * 2 + (r >> 4)) * 512 + (gg * 16 + (r & 15)) * 8 + j0;
            *reinterpret_cast<uint2*>(&Ahi[idx]) =
                make_uint2((unsigned)h0 | ((unsigned)h1 << 16), (unsigned)h2 | ((unsigned)h3 << 16));
            *reinterpret_cast<uint2*>(&Alo[idx]) =
                make_uint2((unsigned)o0 | ((unsigned)o1 << 16), (unsigned)o2 | ((unsigned)o3 << 16));
        }
    }

    f32x4 acc[2][4];
    #pragma unroll
    for (int mt = 0; mt < 2; ++mt)
        #pragma unroll
        for (int f = 0; f < 4; ++f) acc[mt][f] = (f32x4){0.f, 0.f, 0.f, 0.f};

    for (int kt = 0; kt < 8; ++kt) {
        __syncthreads();   // kt==0: publishes A; else: protects Bb overwrite
        const uint4* src = reinterpret_cast<const uint4*>(wc) + kt * 2048 + t;
        #pragma unroll
        for (int u = 0; u < 8; ++u)
            *reinterpret_cast<uint4*>(&Bb[(u * 256 + t) * 8]) = src[u * 256];
        __syncthreads();
        bf16x8 ah[2], al[2];
        #pragma unroll
        for (int mt = 0; mt < 2; ++mt) {
            ah[mt] = *reinterpret_cast<const bf16x8*>(&Ahi[(kt * 2 + mt) * 512 + l * 8]);
            al[mt] = *reinterpret_cast<const bf16x8*>(&Alo[(kt * 2 + mt) * 512 + l * 8]);
        }
        #pragma unroll
        for (int f = 0; f < 4; ++f) {
            const int nt = w * 4 + f;
            const bf16x8 bh = *reinterpret_cast<const bf16x8*>(&Bb[nt * 512 + l * 8]);
            const bf16x8 bl = *reinterpret_cast<const bf16x8*>(&Bb[8192 + nt * 512 + l * 8]);
            #pragma unroll
            for (int mt = 0; mt < 2; ++mt) {
                acc[mt][f] = __builtin_amdgcn_mfma_f32_16x16x32_bf16(ah[mt], bh, acc[mt][f], 0, 0, 0);
                acc[mt][f] = __builtin_amdgcn_mfma_f32_16x16x32_bf16(ah[mt], bl, acc[mt][f], 0, 0, 0);
                acc[mt][f] = __builtin_amdgcn_mfma_f32_16x16x32_bf16(al[mt], bh, acc[mt][f], 0, 0, 0);
            }
        }
    }

    // ---- epilogue: +bias, LN stats (16-lane butterfly + cross-wave LDS), GELU, dot w2 ----
    float b1v[4], gv[4], btv[4], w2v[4];
    #pragma unroll
    for (int f = 0; f < 4; ++f) {
        const int cw = w * 64 + f * 16 + nl;
        b1v[f] = b1[cw]; gv[f] = gam[cw]; btv[f] = bt[cw]; w2v[f] = w2[cw];
    }
    float s1[2][4], s2[2][4];
    #pragma unroll
    for (int mt = 0; mt < 2; ++mt)
        #pragma unroll
        for (int rb = 0; rb < 4; ++rb) {
            float a = 0.f, b = 0.f;
            #pragma unroll
            for (int f = 0; f < 4; ++f) {
                const float h = acc[mt][f][rb] + b1v[f];
                acc[mt][f][rb] = h;
                a += h; b += h * h;
            }
            s1[mt][rb] = a; s2[mt][rb] = b;
        }
    #pragma unroll
    for (int m = 1; m < 16; m <<= 1) {
        #pragma unroll
        for (int mt = 0; mt < 2; ++mt)
            #pragma unroll
            for (int rb = 0; rb < 4; ++rb) {
                s1[mt][rb] += __shfl_xor(s1[mt][rb], m);
                s2[mt][rb] += __shfl_xor(s2[mt][rb], m);
            }
    }
    if (nl == 0) {
        #pragma unroll
        for (int mt = 0; mt < 2; ++mt)
            #pragma unroll
            for (int rb = 0; rb < 4; ++rb) {
                const int row = mt * 16 + gq * 4 + rb;
                red[row * 8 + w * 2]     = s1[mt][rb];
                red[row * 8 + w * 2 + 1] = s2[mt][rb];
            }
    }
    __syncthreads();
    float pp[2][4];
    #pragma unroll
    for (int mt = 0; mt < 2; ++mt)
        #pragma unroll
        for (int rb = 0; rb < 4; ++rb) {
            const int row = mt * 16 + gq * 4 + rb;
            const float4 ra = *reinterpret_cast<const float4*>(&red[row * 8]);
            const float4 rbq = *reinterpret_cast<const float4*>(&red[row * 8 + 4]);
            const float ts1 = ra.x + ra.z + rbq.x + rbq.z;
            const float ts2 = ra.y + ra.w + rbq.y + rbq.w;
            const float mean = ts1 * (1.0f / 256.0f);
            const float var  = ts2 * (1.0f / 256.0f) - mean * mean;
            const float inv  = rsqrtf(var + 1e-5f);
            float p = 0.f;
            #pragma unroll
            for (int f = 0; f < 4; ++f) {
                const float hn = (acc[mt][f][rb] - mean) * inv * gv[f] + btv[f];
                p += gelu_exact(hn) * w2v[f];
            }
            pp[mt][rb] = p;
        }
    #pragma unroll
    for (int m = 1; m < 16; m <<= 1)
        #pragma unroll
        for (int mt = 0; mt < 2; ++mt)
            #pragma unroll
            for (int rb = 0; rb < 4; ++rb) pp[mt][rb] += __shfl_xor(pp[mt][rb], m);
    __syncthreads();  // red reads done
    if (nl == 0) {
        #pragma unroll
        for (int mt = 0; mt < 2; ++mt)
            #pragma unroll
            for (int rb = 0; rb < 4; ++rb)
                red[(mt * 16 + gq * 4 + rb) * 8 + w * 2] = pp[mt][rb];
    }
    __syncthreads();
    if (t < 32)
        imp[r0 + t] = red[t * 8] + red[t * 8 + 2] + red[t * 8 + 4] + red[t * 8 + 6] + b2[0];
}

// ---------------------------------------------------------------------------
// Kernel 2a/2b: segment softmax pieces (unchanged, validated round 4)
// ---------------------------------------------------------------------------
__global__ void segmax_kernel(const float* __restrict__ imp, const int* __restrict__ batch,
                              unsigned* __restrict__ segmax)
{
    const int n = blockIdx.x * blockDim.x + threadIdx.x;
    if (n >= NN) return;
    unsigned u = __float_as_uint(imp[n]);
    u = (u & 0x80000000u) ? ~u : (u | 0x80000000u);
    atomicMax(&segmax[batch[n]], u);
}

__global__ void segexp_kernel(float* __restrict__ imp, const int* __restrict__ batch,
                              const unsigned* __restrict__ segmax, float* __restrict__ segsum)
{
    const int n = blockIdx.x * blockDim.x + threadIdx.x;
    if (n >= NN) return;
    const int b = batch[n];
    const unsigned u = segmax[b];
    const float mx = (u & 0x80000000u) ? __uint_as_float(u ^ 0x80000000u)
                                       : __uint_as_float(~u);
    const float e = expf(imp[n] - mx);
    imp[n] = e;
    atomicAdd(&segsum[b], e);
}

// ---------------------------------------------------------------------------
// Kernel 3: feature MLP (2 MFMA GEMMs) + weighted scatter-add.
// GEMM1 (x@wf1) -> LN+GELU in-register -> f written back into A buffers as
// split-bf16 fragments -> GEMM2 (f@wf2) -> weighted segment scatter.
// Same LDS budget as K1: 65KB, 2 blocks/CU.
// ---------------------------------------------------------------------------
__global__ __launch_bounds__(256, 2) void mlp_feat_mfma(
    const float* __restrict__ x, const int* __restrict__ batch,
    const unsigned short* __restrict__ wc1, const float* __restrict__ b1,
    const float* __restrict__ gam, const float* __restrict__ bt,
    const unsigned short* __restrict__ wc2, const float* __restrict__ b2f,
    const float* __restrict__ e, const float* __restrict__ segsum,
    float* __restrict__ out)
{
    __shared__ __align__(16) unsigned short Ahi[8192];
    __shared__ __align__(16) unsigned short Alo[8192];
    __shared__ __align__(16) unsigned short Bb[16384];
    __shared__ float red[256];
    const int t = threadIdx.x;
    const int w = t >> 6, l = t & 63;
    const int nl = l & 15, gq = l >> 4;
    const int r0 = blockIdx.x * 32;

    // ---- stage x -> A fragments ----
    {
        const int rr = t >> 6;
        const int c0 = (t & 63) * 4;
        const int kt = c0 >> 5, gg = (c0 >> 3) & 3, j0 = c0 & 7;
        #pragma unroll
        for (int p = 0; p < 8; ++p) {
            const int r = rr + p * 4;
            const float4 v = *reinterpret_cast<const float4*>(&x[(size_t)(r0 + r) * DD + c0]);
            const unsigned short h0 = f2bf(v.x), h1 = f2bf(v.y), h2 = f2bf(v.z), h3 = f2bf(v.w);
            const unsigned short o0 = f2bf(v.x - bf2f(h0)), o1 = f2bf(v.y - bf2f(h1));
            const unsigned short o2 = f2bf(v.z - bf2f(h2)), o3 = f2bf(v.w - bf2f(h3));
            const int idx = (kt * 2 + (r >> 4)) * 512 + (gg * 16 + (r & 15)) * 8 + j0;
            *reinterpret_cast<uint2*>(&Ahi[idx]) =
                make_uint2((unsigned)h0 | ((unsigned)h1 << 16), (unsigned)h2 | ((unsigned)h3 << 16));
            *reinterpret_cast<uint2*>(&Alo[idx]) =
                make_uint2((unsigned)o0 | ((unsigned)o1 << 16), (unsigned)o2 | ((unsigned)o3 << 16));
        }
    }

    f32x4 acc[2][4];
    #pragma unroll
    for (int mt = 0; mt < 2; ++mt)
        #pragma unroll
        for (int f = 0; f < 4; ++f) acc[mt][f] = (f32x4){0.f, 0.f, 0.f, 0.f};

    // ---- GEMM1: x @ wf1 ----
    for (int kt = 0; kt < 8; ++kt) {
        __syncthreads();
        const uint4* src = reinterpret_cast<const uint4*>(wc1) + kt * 2048 + t;
        #pragma unroll
        for (int u = 0; u < 8; ++u)
            *reinterpret_cast<uint4*>(&Bb[(u * 256 + t) * 8]) = src[u * 256];
        __syncthreads();
        bf16x8 ah[2], al[2];
        #pragma unroll
        for (int mt = 0; mt < 2; ++mt) {
            ah[mt] = *reinterpret_cast<const bf16x8*>(&Ahi[(kt * 2 + mt) * 512 + l * 8]);
            al[mt] = *reinterpret_cast<const bf16x8*>(&Alo[(kt * 2 + mt) * 512 + l * 8]);
        }
        #pragma unroll
        for (int f = 0; f < 4; ++f) {
            const int nt = w * 4 + f;
            const bf16x8 bh = *reinterpret_cast<const bf16x8*>(&Bb[nt * 512 + l * 8]);
            const bf16x8 bl = *reinterpret_cast<const bf16x8*>(&Bb[8192 + nt * 512 + l * 8]);
            #pragma unroll
            for (int mt = 0; mt < 2; ++mt) {
                acc[mt][f] = __builtin_amdgcn_mfma_f32_16x16x32_bf16(ah[mt], bh, acc[mt][f], 0, 0, 0);
                acc[mt][f] = __builtin_amdgcn_mfma_f32_16x16x32_bf16(ah[mt], bl, acc[mt][f], 0, 0, 0);
                acc[mt][f] = __builtin_amdgcn_mfma_f32_16x16x32_bf16(al[mt], bh, acc[mt][f], 0, 0, 0);
            }
        }
    }

    // ---- LN stats ----
    float b1v[4], gv[4], btv[4];
    #pragma unroll
    for (int f = 0; f < 4; ++f) {
        const int cw = w * 64 + f * 16 + nl;
        b1v[f] = b1[cw]; gv[f] = gam[cw]; btv[f] = bt[cw];
    }
    float s1[2][4], s2[2][4];
    #pragma unroll
    for (int mt = 0; mt < 2; ++mt)
        #pragma unroll
        for (int rb = 0; rb < 4; ++rb) {
            float a = 0.f, b = 0.f;
            #pragma unroll
            for (int f = 0; f < 4; ++f) {
                const float h = acc[mt][f][rb] + b1v[f];
                acc[mt][f][rb] = h;
                a += h; b += h * h;
            }
            s1[mt][rb] = a; s2[mt][rb] = b;
        }
    #pragma unroll
    for (int m = 1; m < 16; m <<= 1) {
        #pragma unroll
        for (int mt = 0; mt < 2; ++mt)
            #pragma unroll
            for (int rb = 0; rb < 4; ++rb) {
                s1[mt][rb] += __shfl_xor(s1[mt][rb], m);
                s2[mt][rb] += __shfl_xor(s2[mt][rb], m);
            }
    }
    if (nl == 0) {
        #pragma unroll
        for (int mt = 0; mt < 2; ++mt)
            #pragma unroll
            for (int rb = 0; rb < 4; ++rb) {
                const int row = mt * 16 + gq * 4 + rb;
                red[row * 8 + w * 2]     = s1[mt][rb];
                red[row * 8 + w * 2 + 1] = s2[mt][rb];
            }
    }
    __syncthreads();   // also guarantees all GEMM1 A/B reads complete

    // ---- LN + GELU -> f, written as split-bf16 A fragments (overwrites x) ----
    #pragma unroll
    for (int mt = 0; mt < 2; ++mt)
        #pragma unroll
        for (int rb = 0; rb < 4; ++rb) {
            const int row = mt * 16 + gq * 4 + rb;
            const float4 ra = *reinterpret_cast<const float4*>(&red[row * 8]);
            const float4 rbq = *reinterpret_cast<const float4*>(&red[row * 8 + 4]);
            const float ts1 = ra.x + ra.z + rbq.x + rbq.z;
            const float ts2 = ra.y + ra.w + rbq.y + rbq.w;
            const float mean = ts1 * (1.0f / 256.0f);
            const float var  = ts2 * (1.0f / 256.0f) - mean * mean;
            const float inv  = rsqrtf(var + 1e-5f);
            #pragma unroll
            for (int f = 0; f < 4; ++f) {
                const float hn = (acc[mt][f][rb] - mean) * inv * gv[f] + btv[f];
                const float fv = gelu_exact(hn);
                const unsigned short fh = f2bf(fv);
                const unsigned short fl = f2bf(fv - bf2f(fh));
                const int col = w * 64 + f * 16 + nl;   // k-index for GEMM2
                const int kt2 = col >> 5, gg = (col >> 3) & 3, j = col & 7;
                const int idx = (kt2 * 2 + mt) * 512 + (gg * 16 + (row & 15)) * 8 + j;
                Ahi[idx] = fh;
                Alo[idx] = fl;
            }
        }

    // ---- GEMM2: f @ wf2 ----
    f32x4 acc2[2][4];
    #pragma unroll
    for (int mt = 0; mt < 2; ++mt)
        #pragma unroll
        for (int f = 0; f < 4; ++f) acc2[mt][f] = (f32x4){0.f, 0.f, 0.f, 0.f};

    for (int kt = 0; kt < 8; ++kt) {
        __syncthreads();   // kt==0: publishes f-fragments
        const uint4* src = reinterpret_cast<const uint4*>(wc2) + kt * 2048 + t;
        #pragma unroll
        for (int u = 0; u < 8; ++u)
            *reinterpret_cast<uint4*>(&Bb[(u * 256 + t) * 8]) = src[u * 256];
        __syncthreads();
        bf16x8 ah[2], al[2];
        #pragma unroll
        for (int mt = 0; mt < 2; ++mt) {
            ah[mt] = *reinterpret_cast<const bf16x8*>(&Ahi[(kt * 2 + mt) * 512 + l * 8]);
            al[mt] = *reinterpret_cast<const bf16x8*>(&Alo[(kt * 2 + mt) * 512 + l * 8]);
        }
        #pragma unroll
        for (int f = 0; f < 4; ++f) {
            const int nt = w * 4 + f;
            const bf16x8 bh = *reinterpret_cast<const bf16x8*>(&Bb[nt * 512 + l * 8]);
            const bf16x8 bl = *reinterpret_cast<const bf16x8*>(&Bb[8192 + nt * 512 + l * 8]);
            #pragma unroll
            for (int mt = 0; mt < 2; ++mt) {
                acc2[mt][f] = __builtin_amdgcn_mfma_f32_16x16x32_bf16(ah[mt], bh, acc2[mt][f], 0, 0, 0);
                acc2[mt][f] = __builtin_amdgcn_mfma_f32_16x16x32_bf16(ah[mt], bl, acc2[mt][f], 0, 0, 0);
                acc2[mt][f] = __builtin_amdgcn_mfma_f32_16x16x32_bf16(al[mt], bh, acc2[mt][f], 0, 0, 0);
            }
        }
    }

    // ---- weighted segment scatter ----
    const int bfirst = batch[r0];
    const int blast  = batch[r0 + 31];
    const bool uni = (bfirst == blast);
    float bf2v[4]; int cw[4];
    #pragma unroll
    for (int f = 0; f < 4; ++f) {
        cw[f] = w * 64 + f * 16 + nl;
        bf2v[f] = b2f[cw[f]];
    }
    if (uni) {
        const float ssinv = 1.0f / segsum[bfirst];
        float wv[2][4];
        #pragma unroll
        for (int mt = 0; mt < 2; ++mt)
            #pragma unroll
            for (int rb = 0; rb < 4; ++rb)
                wv[mt][rb] = e[r0 + mt * 16 + gq * 4 + rb] * ssinv;
        #pragma unroll
        for (int f = 0; f < 4; ++f) {
            float s = 0.f;
            #pragma unroll
            for (int mt = 0; mt < 2; ++mt)
                #pragma unroll
                for (int rb = 0; rb < 4; ++rb)
                    s += (acc2[mt][f][rb] + bf2v[f]) * wv[mt][rb];
            s += __shfl_xor(s, 16);
            s += __shfl_xor(s, 32);
            if (l < 16) atomicAdd(&out[bfirst * 256 + cw[f]], s);
        }
    } else {
        #pragma unroll
        for (int mt = 0; mt < 2; ++mt)
            #pragma unroll
            for (int rb = 0; rb < 4; ++rb) {
                const int r = r0 + mt * 16 + gq * 4 + rb;
                const int b = batch[r];
                const float wv = e[r] / segsum[b];
                #pragma unroll
                for (int f = 0; f < 4; ++f)
                    atomicAdd(&out[b * 256 + cw[f]], (acc2[mt][f][rb] + bf2v[f]) * wv);
            }
    }
}

// ---------------------------------------------------------------------------
extern "C" void kernel_launch(void* const* d_in, const int* in_sizes, int n_in,
                              void* d_out, int out_size, void* d_ws, size_t ws_size,
                              hipStream_t stream)
{
    const float* x    = (const float*)d_in[0];
    const int*   batch= (const int*)  d_in[1];
    const float* wi1  = (const float*)d_in[2];
    const float* bi1  = (const float*)d_in[3];
    const float* gi   = (const float*)d_in[4];
    const float* bti  = (const float*)d_in[5];
    const float* wi2  = (const float*)d_in[6];
    const float* bi2  = (const float*)d_in[7];
    const float* wf1  = (const float*)d_in[8];
    const float* bf1  = (const float*)d_in[9];
    const float* gf   = (const float*)d_in[10];
    const float* btf  = (const float*)d_in[11];
    const float* wf2  = (const float*)d_in[12];
    const float* bf2  = (const float*)d_in[13];
    float* out = (float*)d_out;

    // ws layout: imp/e [NN]f32 | segmax [BB]u32 | segsum [BB]f32 | 3x converted weights
    char* wsb = (char*)d_ws;
    float*    imp    = (float*)wsb;
    unsigned* segmax = (unsigned*)(wsb + (size_t)NN * 4);
    float*    segsum = (float*)(wsb + (size_t)NN * 4 + (size_t)BB * 4);
    unsigned short* c1  = (unsigned short*)(wsb + (size_t)NN * 4 + (size_t)BB * 8);
    unsigned short* cf1 = c1 + 131072;
    unsigned short* cf2 = c1 + 262144;

    hipMemsetAsync(d_out, 0, (size_t)BB * DD * sizeof(float), stream);
    hipMemsetAsync((void*)segmax, 0, (size_t)BB * 2 * sizeof(float), stream);

    convert_weights_kernel<<<768, 256, 0, stream>>>(wi1, wf1, wf2, c1, cf1, cf2);
    mlp_imp_mfma<<<NN / 32, 256, 0, stream>>>(x, c1, bi1, gi, bti, wi2, bi2, imp);
    segmax_kernel<<<(NN + 255) / 256, 256, 0, stream>>>(imp, batch, segmax);
    segexp_kernel<<<(NN + 255) / 256, 256, 0, stream>>>(imp, batch, segmax, segsum);
    mlp_feat_mfma<<<NN / 32, 256, 0, stream>>>(x, batch, cf1, bf1, gf, btf, cf2, bf2,
                                               imp, segsum, out);
}